// Round 3
// baseline (309.268 us; speedup 1.0000x reference)
//
#include <hip/hip_runtime.h>

// StationLoss: B=16, H=W=2048, S=5000, KERNEL_SIZE=3, METRIC=MSE
// Kernel 1: one WAVE per block (64 thr), one thread per station ->
//           3x3 masked window mean -> squared error -> wave reduction ->
//           one partial per block in d_ws (plain store, no LDS, no syncthreads).
// Kernel 2: one wave reduces the 1250 partials, writes scalar mean to d_out.
// No atomics / no memset: fully deterministic, no buffer init needed.
//
// Timing note: measured dur_us (~308) is dominated by harness reset traffic
// (1 GiB d_ws re-poison ~163us @82% HBM + 256MB input restore ~81us); the two
// kernels here are ~10-20us combined (never in rocprof top-5).

#define BB 16
#define HH 2048
#define WW 2048
#define SS 5000
#define NSTATIONS (BB * SS)
#define THREADS 64
#define NBLOCKS ((NSTATIONS + THREADS - 1) / THREADS)   // 1250

__global__ __launch_bounds__(THREADS) void station_partial_kernel(
    const float* __restrict__ pred,       // (B,1,H,W)
    const int2*  __restrict__ pos,        // (B,S,2) -> {px, py}
    const float* __restrict__ runoff,     // (B,S)
    float* __restrict__ partials)         // (NBLOCKS,)
{
    int t = blockIdx.x * THREADS + threadIdx.x;
    float contrib = 0.0f;
    if (t < NSTATIONS) {
        int b = t / SS;
        int2 p = pos[t];                  // p.x = px (width), p.y = py (height)
        int px = p.x;
        int py = p.y;
        const float* img = pred + (size_t)b * (size_t)(HH * WW);

        float sum = 0.0f;
        float cnt = 0.0f;
        #pragma unroll
        for (int dy = -1; dy <= 1; ++dy) {
            int y = py + dy;
            bool yok = (y >= 0) & (y < HH);
            int yc = min(max(y, 0), HH - 1);
            const float* row = img + (size_t)yc * WW;
            #pragma unroll
            for (int dx = -1; dx <= 1; ++dx) {
                int x = px + dx;
                bool ok = yok & (x >= 0) & (x < WW);
                int xc = min(max(x, 0), WW - 1);
                float v = row[xc];                 // always in-bounds (clamped)
                float m = ok ? 1.0f : 0.0f;
                sum += v * m;
                cnt += m;
            }
        }
        float avg = sum / cnt;            // cnt >= 4 always
        float d = avg - runoff[t];
        contrib = d * d;
    }

    // wave-64 reduction, lane 0 stores the block partial
    #pragma unroll
    for (int off = 32; off > 0; off >>= 1)
        contrib += __shfl_down(contrib, off, 64);
    if (threadIdx.x == 0)
        partials[blockIdx.x] = contrib;
}

__global__ __launch_bounds__(64) void reduce_kernel(
    const float* __restrict__ partials, float* __restrict__ out)
{
    float v = 0.0f;
    #pragma unroll
    for (int i = threadIdx.x; i < NBLOCKS; i += 64) v += partials[i];
    #pragma unroll
    for (int off = 32; off > 0; off >>= 1)
        v += __shfl_down(v, off, 64);
    if (threadIdx.x == 0)
        out[0] = v * (1.0f / (float)NSTATIONS);
}

extern "C" void kernel_launch(void* const* d_in, const int* in_sizes, int n_in,
                              void* d_out, int out_size, void* d_ws, size_t ws_size,
                              hipStream_t stream) {
    const float* pred   = (const float*)d_in[0];
    const int2*  pos    = (const int2*)d_in[1];
    const float* runoff = (const float*)d_in[2];
    float* out      = (float*)d_out;
    float* partials = (float*)d_ws;

    station_partial_kernel<<<NBLOCKS, THREADS, 0, stream>>>(pred, pos, runoff, partials);
    reduce_kernel<<<1, 64, 0, stream>>>(partials, out);
}